// Round 5
// baseline (61.693 us; speedup 1.0000x reference)
//
#include <hip/hip_runtime.h>
#include <math.h>

#define BATCH 8192
#define DIM 4096
#define DSTRIDE 83  // floats per row in the D table

// ---------------------------------------------------------------------------
// Compile-time x-rotation constant tables:
//   X_l(beta) = P0 + sum_mu cos(mu*beta)*A_mu + sin(mu*beta)*B_mu
// Layout (495 floats): l=1 @0 (27), l=2 @27 (125), l=3 @152 (343)
// ---------------------------------------------------------------------------

struct FT { float v[495]; };

constexpr double csqrt(double x) {
  double g = x > 1.0 ? x : 1.0;
  for (int i = 0; i < 50; ++i) g = 0.5 * (g + x / g);
  return g;
}

constexpr void mmc(int n, const double* A, const double* B, double* C) {
  for (int i = 0; i < n; ++i)
    for (int j = 0; j < n; ++j) {
      double s = 0.0;
      for (int k = 0; k < n; ++k) s += A[i * n + k] * B[k * n + j];
      C[i * n + j] = s;
    }
}

constexpr FT compute_ft() {
  FT o{};
  for (int l = 1; l <= 3; ++l) {
    const int n = 2 * l + 1, nn = n * n;
    double JX[49] = {}, UR[49] = {}, UI[49] = {};
    for (int a = 0; a < n - 1; ++a) {
      double m = (double)(a - l);
      double v = 0.5 * csqrt((double)(l * (l + 1)) - m * (m + 1.0));
      JX[(a + 1) * n + a] = v;
      JX[a * n + (a + 1)] = v;
    }
    UR[l * n + l] = 1.0;
    const double s = csqrt(0.5);
    for (int mu = 1; mu <= l; ++mu) {
      double sg = (mu & 1) ? -1.0 : 1.0;
      UR[(l + mu) * n + (l - mu)] = s;
      UR[(l + mu) * n + (l + mu)] = s * sg;
      UI[(l - mu) * n + (l - mu)] = s;
      UI[(l - mu) * n + (l + mu)] = -s * sg;
    }
    double MR[49] = {}, MI[49] = {};
    mmc(n, UR, JX, MR);
    mmc(n, UI, JX, MI);
    double K[49] = {};
    for (int a = 0; a < n; ++a)
      for (int b = 0; b < n; ++b) {
        double acc = 0.0;
        for (int c = 0; c < n; ++c)
          acc += MI[a * n + c] * UR[b * n + c] - MR[a * n + c] * UI[b * n + c];
        K[a * n + b] = acc;
      }
    const double TH = 0.78539816339744830962;
    double S[49] = {}, P[49] = {}, T[49] = {};
    for (int i = 0; i < nn; ++i) S[i] = K[i] * (TH / 16.0);
    for (int i = 0; i < n; ++i) P[i * n + i] = 1.0;
    for (int t = 12; t >= 1; --t) {
      mmc(n, S, P, T);
      double inv = 1.0 / (double)t;
      for (int i = 0; i < nn; ++i) P[i] = T[i] * inv;
      for (int i = 0; i < n; ++i) P[i * n + i] += 1.0;
    }
    for (int q = 0; q < 4; ++q) {
      mmc(n, P, P, T);
      for (int i = 0; i < nn; ++i) P[i] = T[i];
    }
    double acc[7][49] = {};
    double Ek[49] = {}, Et[49] = {};
    for (int i = 0; i < n; ++i) Ek[i * n + i] = 1.0;
    const double r2 = csqrt(0.5);
    const double c8[8] = {1.0, r2, 0.0, -r2, -1.0, -r2, 0.0, r2};
    const double s8[8] = {0.0, r2, 1.0, r2, 0.0, -r2, -1.0, -r2};
    for (int k = 0; k < 8; ++k) {
      for (int i = 0; i < nn; ++i) acc[0][i] += 0.125 * Ek[i];
      for (int mu = 1; mu <= l; ++mu) {
        int a8 = (mu * k) & 7;
        double cc = 0.25 * c8[a8], ss = 0.25 * s8[a8];
        for (int i = 0; i < nn; ++i) {
          acc[2 * mu - 1][i] += cc * Ek[i];
          acc[2 * mu][i] += ss * Ek[i];
        }
      }
      mmc(n, Ek, P, Et);
      for (int i = 0; i < nn; ++i) Ek[i] = Et[i];
    }
    int base = (l == 1) ? 0 : ((l == 2) ? 27 : 152);
    for (int t = 0; t <= 2 * l; ++t)
      for (int i = 0; i < nn; ++i) o.v[base + t * nn + i] = (float)acc[t][i];
  }
  return o;
}

__device__ __constant__ FT c_tb = compute_ft();

typedef float vf4 __attribute__((ext_vector_type(4)));

__device__ __forceinline__ vf4 vfma4(float a, vf4 v, vf4 acc) { return acc + a * v; }

// ---------------------------------------------------------------------------
// D-entry evaluation shared by both paths
// ---------------------------------------------------------------------------
__device__ __forceinline__ float d_entry(int l, int n, int basec, int i, int j,
                                         const float* cb, const float* sb,
                                         const float* ca, const float* sa,
                                         const float* cg, const float* sg) {
  const float* C = c_tb.v + basec;
  int ip = n - 1 - i, jp = n - 1 - j;
  float xij = 0.f, xijp = 0.f, xipj = 0.f, xipjp = 0.f;
  for (int tt = 0; tt <= 2 * l; ++tt) {
    float coef = (tt == 0) ? 1.f : ((tt & 1) ? cb[(tt + 1) >> 1] : sb[tt >> 1]);
    const float* M = C + tt * n * n;
    xij   = fmaf(coef, M[i * n + j],   xij);
    xijp  = fmaf(coef, M[i * n + jp],  xijp);
    xipj  = fmaf(coef, M[ip * n + j],  xipj);
    xipjp = fmaf(coef, M[ip * n + jp], xipjp);
  }
  int di = i - l, dj = j - l;
  float cai = ca[di < 0 ? -di : di];
  float sai = di < 0 ? -sa[-di] : sa[di];
  float cgj = cg[dj < 0 ? -dj : dj];
  float sgj = dj < 0 ? -sg[-dj] : sg[dj];
  return (cai * xij + sai * xipj) * cgj - (cai * xijp + sai * xipjp) * sgj;
}

__device__ __forceinline__ void angle_tables(float t, float* c, float* s) {
  c[0] = 1.f; s[0] = 0.f;
  sincosf(t, &s[1], &c[1]);
  c[2] = c[1] * c[1] - s[1] * s[1];
  s[2] = 2.f * s[1] * c[1];
  c[3] = c[2] * c[1] - s[2] * s[1];
  s[3] = s[2] * c[1] + c[2] * s[1];
}

// ---------------------------------------------------------------------------
// Kernel 1: one thread per batch row -> 83 D entries into ws
// ---------------------------------------------------------------------------
__global__ __launch_bounds__(256) void build_D(
    const float* __restrict__ gamma, const float* __restrict__ beta,
    const float* __restrict__ alpha, float* __restrict__ Dws) {
  int b = blockIdx.x * 256 + threadIdx.x;
  if (b >= BATCH) return;
  float cb[4], sb[4], ca[4], sa[4], cg[4], sg[4];
  angle_tables(beta[b], cb, sb);
  angle_tables(alpha[b], ca, sa);
  angle_tables(gamma[b], cg, sg);
  float* Drow = Dws + (size_t)b * DSTRIDE;
  int baseD = 0;
  #pragma unroll
  for (int l = 1; l <= 3; ++l) {
    int n = 2 * l + 1;
    int basec = (l == 1) ? 0 : ((l == 2) ? 27 : 152);
    for (int i = 0; i < n; ++i)
      for (int j = 0; j < n; ++j)
        Drow[baseD + i * n + j] =
            d_entry(l, n, basec, i, j, cb, sb, ca, sa, cg, sg);
    baseD += n * n;
  }
}

// ---------------------------------------------------------------------------
// Kernel 2: pure streamer. 1 block = 4 rows, 256 threads. D from ws via LDS.
// All 16 loads issued and PINNED live (asm) before compute; nt stores.
// ---------------------------------------------------------------------------
__global__ __launch_bounds__(256, 4) void rot_stream(
    const float* __restrict__ Dws, const float* __restrict__ x,
    float* __restrict__ out) {
  __shared__ float Dl[4 * DSTRIDE];
  const int tid = threadIdx.x;
  const int b0 = blockIdx.x * 4;
  const int lane = tid & 63;
  const int row = tid >> 6;
  const size_t b = (size_t)(b0 + row);
  const vf4* __restrict__ xin = (const vf4*)x + b * 1024;
  vf4* __restrict__ xo = (vf4*)out + b * 1024;

  // issue ALL x loads first: 16 vf4 in flight per lane
  vf4 v0 = xin[lane];
  vf4 v1[3], v2[5], v3[7];
  #pragma unroll
  for (int j = 0; j < 3; ++j) v1[j] = xin[64 + j * 64 + lane];
  #pragma unroll
  for (int j = 0; j < 5; ++j) v2[j] = xin[256 + j * 64 + lane];
  #pragma unroll
  for (int j = 0; j < 7; ++j) v3[j] = xin[576 + j * 64 + lane];

  // stage D for the block's 4 rows (332 floats, coalesced)
  for (int e = tid; e < 4 * DSTRIDE; e += 256)
    Dl[e] = Dws[(size_t)b0 * DSTRIDE + e];
  __syncthreads();

  // pin all loaded values live here (defeats load-sinking; one vmcnt wait)
  asm volatile("" ::"v"(v0), "v"(v1[0]), "v"(v1[1]), "v"(v1[2]), "v"(v2[0]),
               "v"(v2[1]), "v"(v2[2]), "v"(v2[3]), "v"(v2[4]), "v"(v3[0]),
               "v"(v3[1]), "v"(v3[2]), "v"(v3[3]), "v"(v3[4]), "v"(v3[5]),
               "v"(v3[6]));

  const float* D = Dl + row * DSTRIDE;

  __builtin_nontemporal_store(v0, &xo[lane]);

  #pragma unroll
  for (int i = 0; i < 3; ++i) {
    vf4 o = (vf4)(0.f);
    #pragma unroll
    for (int j = 0; j < 3; ++j) o = vfma4(D[i * 3 + j], v1[j], o);
    __builtin_nontemporal_store(o, &xo[64 + i * 64 + lane]);
  }
  #pragma unroll
  for (int i = 0; i < 5; ++i) {
    vf4 o = (vf4)(0.f);
    #pragma unroll
    for (int j = 0; j < 5; ++j) o = vfma4(D[9 + i * 5 + j], v2[j], o);
    __builtin_nontemporal_store(o, &xo[256 + i * 64 + lane]);
  }
  #pragma unroll
  for (int i = 0; i < 7; ++i) {
    vf4 o = (vf4)(0.f);
    #pragma unroll
    for (int j = 0; j < 7; ++j) o = vfma4(D[34 + i * 7 + j], v3[j], o);
    __builtin_nontemporal_store(o, &xo[576 + i * 64 + lane]);
  }
}

// ---------------------------------------------------------------------------
// Fallback fused kernel (ws too small) — round-4 version
// ---------------------------------------------------------------------------
__global__ __launch_bounds__(256) void rot_fused(
    const float* __restrict__ gamma, const float* __restrict__ beta,
    const float* __restrict__ alpha, const float* __restrict__ x,
    float* __restrict__ out) {
  __shared__ float Dl[4][DSTRIDE];
  const int tid = threadIdx.x;
  const int b0 = blockIdx.x * 4;

  for (int e = tid; e < 4 * DSTRIDE; e += 256) {
    int row = e / DSTRIDE;
    int idx = e - row * DSTRIDE;
    int l, n, basec, r;
    if (idx < 9)       { l = 1; n = 3; basec = 0;   r = idx; }
    else if (idx < 34) { l = 2; n = 5; basec = 27;  r = idx - 9; }
    else               { l = 3; n = 7; basec = 152; r = idx - 34; }
    int i = r / n, j = r - i * n;
    int b = b0 + row;
    float cb[4], sb[4], ca[4], sa[4], cg[4], sg[4];
    angle_tables(beta[b], cb, sb);
    angle_tables(alpha[b], ca, sa);
    angle_tables(gamma[b], cg, sg);
    Dl[row][idx] = d_entry(l, n, basec, i, j, cb, sb, ca, sa, cg, sg);
  }
  __syncthreads();

  const int lane = tid & 63;
  const int row = tid >> 6;
  const size_t b = (size_t)(b0 + row);
  const vf4* __restrict__ xin = (const vf4*)x + b * 1024;
  vf4* __restrict__ xo = (vf4*)out + b * 1024;
  const float* D = Dl[row];

  vf4 v0 = xin[lane];
  vf4 v1[3], v2[5], v3[7];
  #pragma unroll
  for (int j = 0; j < 3; ++j) v1[j] = xin[64 + j * 64 + lane];
  #pragma unroll
  for (int j = 0; j < 5; ++j) v2[j] = xin[256 + j * 64 + lane];
  #pragma unroll
  for (int j = 0; j < 7; ++j) v3[j] = xin[576 + j * 64 + lane];

  __builtin_nontemporal_store(v0, &xo[lane]);
  #pragma unroll
  for (int i = 0; i < 3; ++i) {
    vf4 o = (vf4)(0.f);
    #pragma unroll
    for (int j = 0; j < 3; ++j) o = vfma4(D[i * 3 + j], v1[j], o);
    __builtin_nontemporal_store(o, &xo[64 + i * 64 + lane]);
  }
  #pragma unroll
  for (int i = 0; i < 5; ++i) {
    vf4 o = (vf4)(0.f);
    #pragma unroll
    for (int j = 0; j < 5; ++j) o = vfma4(D[9 + i * 5 + j], v2[j], o);
    __builtin_nontemporal_store(o, &xo[256 + i * 64 + lane]);
  }
  #pragma unroll
  for (int i = 0; i < 7; ++i) {
    vf4 o = (vf4)(0.f);
    #pragma unroll
    for (int j = 0; j < 7; ++j) o = vfma4(D[34 + i * 7 + j], v3[j], o);
    __builtin_nontemporal_store(o, &xo[576 + i * 64 + lane]);
  }
}

extern "C" void kernel_launch(void* const* d_in, const int* in_sizes, int n_in,
                              void* d_out, int out_size, void* d_ws, size_t ws_size,
                              hipStream_t stream) {
  const float* gamma = (const float*)d_in[0];
  const float* beta  = (const float*)d_in[1];
  const float* alpha = (const float*)d_in[2];
  const float* x     = (const float*)d_in[3];
  float* out = (float*)d_out;

  const size_t need = (size_t)BATCH * DSTRIDE * sizeof(float);
  if (ws_size >= need) {
    float* Dws = (float*)d_ws;
    build_D<<<BATCH / 256, 256, 0, stream>>>(gamma, beta, alpha, Dws);
    rot_stream<<<BATCH / 4, 256, 0, stream>>>(Dws, x, out);
  } else {
    rot_fused<<<BATCH / 4, 256, 0, stream>>>(gamma, beta, alpha, x, out);
  }
}

// Round 6
// 58.325 us; speedup vs baseline: 1.0577x; 1.0577x over previous
//
#include <hip/hip_runtime.h>
#include <math.h>

#define BATCH 8192
#define DIM 4096
#define DSTRIDE 83   // D entries per row
#define DPAD 96      // padded LDS stride
#define GRID 512     // blocks; 2048 row-groups / 512 = 4 iterations per block

// ---------------------------------------------------------------------------
// Compile-time x-rotation constant tables:
//   X_l(beta) = P0 + sum_mu cos(mu*beta)*A_mu + sin(mu*beta)*B_mu
// Layout (495 floats): l=1 @0 (27), l=2 @27 (125), l=3 @152 (343)
// ---------------------------------------------------------------------------

struct FT { float v[495]; };

constexpr double csqrt(double x) {
  double g = x > 1.0 ? x : 1.0;
  for (int i = 0; i < 50; ++i) g = 0.5 * (g + x / g);
  return g;
}

constexpr void mmc(int n, const double* A, const double* B, double* C) {
  for (int i = 0; i < n; ++i)
    for (int j = 0; j < n; ++j) {
      double s = 0.0;
      for (int k = 0; k < n; ++k) s += A[i * n + k] * B[k * n + j];
      C[i * n + j] = s;
    }
}

constexpr FT compute_ft() {
  FT o{};
  for (int l = 1; l <= 3; ++l) {
    const int n = 2 * l + 1, nn = n * n;
    double JX[49] = {}, UR[49] = {}, UI[49] = {};
    for (int a = 0; a < n - 1; ++a) {
      double m = (double)(a - l);
      double v = 0.5 * csqrt((double)(l * (l + 1)) - m * (m + 1.0));
      JX[(a + 1) * n + a] = v;
      JX[a * n + (a + 1)] = v;
    }
    UR[l * n + l] = 1.0;
    const double s = csqrt(0.5);
    for (int mu = 1; mu <= l; ++mu) {
      double sg = (mu & 1) ? -1.0 : 1.0;
      UR[(l + mu) * n + (l - mu)] = s;
      UR[(l + mu) * n + (l + mu)] = s * sg;
      UI[(l - mu) * n + (l - mu)] = s;
      UI[(l - mu) * n + (l + mu)] = -s * sg;
    }
    double MR[49] = {}, MI[49] = {};
    mmc(n, UR, JX, MR);
    mmc(n, UI, JX, MI);
    double K[49] = {};
    for (int a = 0; a < n; ++a)
      for (int b = 0; b < n; ++b) {
        double acc = 0.0;
        for (int c = 0; c < n; ++c)
          acc += MI[a * n + c] * UR[b * n + c] - MR[a * n + c] * UI[b * n + c];
        K[a * n + b] = acc;
      }
    const double TH = 0.78539816339744830962;
    double S[49] = {}, P[49] = {}, T[49] = {};
    for (int i = 0; i < nn; ++i) S[i] = K[i] * (TH / 16.0);
    for (int i = 0; i < n; ++i) P[i * n + i] = 1.0;
    for (int t = 12; t >= 1; --t) {
      mmc(n, S, P, T);
      double inv = 1.0 / (double)t;
      for (int i = 0; i < nn; ++i) P[i] = T[i] * inv;
      for (int i = 0; i < n; ++i) P[i * n + i] += 1.0;
    }
    for (int q = 0; q < 4; ++q) {
      mmc(n, P, P, T);
      for (int i = 0; i < nn; ++i) P[i] = T[i];
    }
    double acc[7][49] = {};
    double Ek[49] = {}, Et[49] = {};
    for (int i = 0; i < n; ++i) Ek[i * n + i] = 1.0;
    const double r2 = csqrt(0.5);
    const double c8[8] = {1.0, r2, 0.0, -r2, -1.0, -r2, 0.0, r2};
    const double s8[8] = {0.0, r2, 1.0, r2, 0.0, -r2, -1.0, -r2};
    for (int k = 0; k < 8; ++k) {
      for (int i = 0; i < nn; ++i) acc[0][i] += 0.125 * Ek[i];
      for (int mu = 1; mu <= l; ++mu) {
        int a8 = (mu * k) & 7;
        double cc = 0.25 * c8[a8], ss = 0.25 * s8[a8];
        for (int i = 0; i < nn; ++i) {
          acc[2 * mu - 1][i] += cc * Ek[i];
          acc[2 * mu][i] += ss * Ek[i];
        }
      }
      mmc(n, Ek, P, Et);
      for (int i = 0; i < nn; ++i) Ek[i] = Et[i];
    }
    int base = (l == 1) ? 0 : ((l == 2) ? 27 : 152);
    for (int t = 0; t <= 2 * l; ++t)
      for (int i = 0; i < nn; ++i) o.v[base + t * nn + i] = (float)acc[t][i];
  }
  return o;
}

__device__ __constant__ FT c_tb = compute_ft();

typedef float vf4 __attribute__((ext_vector_type(4)));

__device__ __forceinline__ vf4 vfma4(float a, vf4 v, vf4 acc) { return acc + a * v; }

__device__ __forceinline__ float d_entry(int l, int n, int basec, int i, int j,
                                         const float* cb, const float* sb,
                                         const float* ca, const float* sa,
                                         const float* cg, const float* sg) {
  const float* C = c_tb.v + basec;
  int ip = n - 1 - i, jp = n - 1 - j;
  float xij = 0.f, xijp = 0.f, xipj = 0.f, xipjp = 0.f;
  for (int tt = 0; tt <= 2 * l; ++tt) {
    float coef = (tt == 0) ? 1.f : ((tt & 1) ? cb[(tt + 1) >> 1] : sb[tt >> 1]);
    const float* M = C + tt * n * n;
    xij   = fmaf(coef, M[i * n + j],   xij);
    xijp  = fmaf(coef, M[i * n + jp],  xijp);
    xipj  = fmaf(coef, M[ip * n + j],  xipj);
    xipjp = fmaf(coef, M[ip * n + jp], xipjp);
  }
  int di = i - l, dj = j - l;
  float cai = ca[di < 0 ? -di : di];
  float sai = di < 0 ? -sa[-di] : sa[di];
  float cgj = cg[dj < 0 ? -dj : dj];
  float sgj = dj < 0 ? -sg[-dj] : sg[dj];
  return (cai * xij + sai * xipj) * cgj - (cai * xijp + sai * xipjp) * sgj;
}

__device__ __forceinline__ void angle_tables(float t, float* c, float* s) {
  c[0] = 1.f; s[0] = 0.f;
  sincosf(t, &s[1], &c[1]);
  c[2] = c[1] * c[1] - s[1] * s[1];
  s[2] = 2.f * s[1] * c[1];
  c[3] = c[2] * c[1] - s[2] * s[1];
  s[3] = s[2] * c[1] + c[2] * s[1];
}

// ---------------------------------------------------------------------------
// Fused grid-stride streamer. 1 block = 256 threads; per iteration the block
// handles 4 rows (1 row per wave, 16 float4 per lane). x-loads are issued
// FIRST and pinned live, the D-build trig overlaps their HBM latency, one
// barrier, then FMA + nt stores. D is double-buffered in LDS so iteration
// i+1's D-build never races iteration i's consume (single barrier per iter).
// ---------------------------------------------------------------------------
__global__ __launch_bounds__(256) void rot_gs(
    const float* __restrict__ gamma, const float* __restrict__ beta,
    const float* __restrict__ alpha, const float* __restrict__ x,
    float* __restrict__ out) {
  __shared__ float Dl[2][4][DPAD];
  const int tid = threadIdx.x;
  const int lane = tid & 63;
  const int wv = tid >> 6;

  int p = 0;
  for (int g = blockIdx.x; g < BATCH / 4; g += GRID, p ^= 1) {
    const int b0 = g * 4;
    const size_t b = (size_t)(b0 + wv);
    const vf4* __restrict__ xin = (const vf4*)x + b * 1024;
    vf4* __restrict__ xo = (vf4*)out + b * 1024;

    // ---- 1. issue ALL x loads for this iteration (16 vf4 per lane) ----
    vf4 v0 = xin[lane];
    vf4 v1[3], v2[5], v3[7];
    #pragma unroll
    for (int j = 0; j < 3; ++j) v1[j] = xin[64 + j * 64 + lane];
    #pragma unroll
    for (int j = 0; j < 5; ++j) v2[j] = xin[256 + j * 64 + lane];
    #pragma unroll
    for (int j = 0; j < 7; ++j) v3[j] = xin[576 + j * 64 + lane];
    // pin: forces the 16 loads to be issued by this point (no sinking), so
    // the D-build below overlaps their HBM latency
    asm volatile("" ::"v"(v0), "v"(v1[0]), "v"(v1[1]), "v"(v1[2]), "v"(v2[0]),
                 "v"(v2[1]), "v"(v2[2]), "v"(v2[3]), "v"(v2[4]), "v"(v3[0]),
                 "v"(v3[1]), "v"(v3[2]), "v"(v3[3]), "v"(v3[4]), "v"(v3[5]),
                 "v"(v3[6]));

    // ---- 2. build D for the block's 4 rows into Dl[p] ----
    for (int e = tid; e < 4 * DSTRIDE; e += 256) {
      int row = e / DSTRIDE;
      int idx = e - row * DSTRIDE;
      int l, n, basec, r;
      if (idx < 9)       { l = 1; n = 3; basec = 0;   r = idx; }
      else if (idx < 34) { l = 2; n = 5; basec = 27;  r = idx - 9; }
      else               { l = 3; n = 7; basec = 152; r = idx - 34; }
      int i = r / n, j = r - i * n;
      int bb = b0 + row;
      float cb[4], sbv[4], ca[4], sav[4], cg[4], sgv[4];
      angle_tables(beta[bb], cb, sbv);
      angle_tables(alpha[bb], ca, sav);
      angle_tables(gamma[bb], cg, sgv);
      Dl[p][row][idx] = d_entry(l, n, basec, i, j, cb, sbv, ca, sav, cg, sgv);
    }
    __syncthreads();

    // ---- 3. consume: FMA + nt stores ----
    const float* D = Dl[p][wv];

    __builtin_nontemporal_store(v0, &xo[lane]);
    #pragma unroll
    for (int i = 0; i < 3; ++i) {
      vf4 o = (vf4)(0.f);
      #pragma unroll
      for (int j = 0; j < 3; ++j) o = vfma4(D[i * 3 + j], v1[j], o);
      __builtin_nontemporal_store(o, &xo[64 + i * 64 + lane]);
    }
    #pragma unroll
    for (int i = 0; i < 5; ++i) {
      vf4 o = (vf4)(0.f);
      #pragma unroll
      for (int j = 0; j < 5; ++j) o = vfma4(D[9 + i * 5 + j], v2[j], o);
      __builtin_nontemporal_store(o, &xo[256 + i * 64 + lane]);
    }
    #pragma unroll
    for (int i = 0; i < 7; ++i) {
      vf4 o = (vf4)(0.f);
      #pragma unroll
      for (int j = 0; j < 7; ++j) o = vfma4(D[34 + i * 7 + j], v3[j], o);
      __builtin_nontemporal_store(o, &xo[576 + i * 64 + lane]);
    }
  }
}

extern "C" void kernel_launch(void* const* d_in, const int* in_sizes, int n_in,
                              void* d_out, int out_size, void* d_ws, size_t ws_size,
                              hipStream_t stream) {
  const float* gamma = (const float*)d_in[0];
  const float* beta  = (const float*)d_in[1];
  const float* alpha = (const float*)d_in[2];
  const float* x     = (const float*)d_in[3];
  float* out = (float*)d_out;

  rot_gs<<<GRID, 256, 0, stream>>>(gamma, beta, alpha, x, out);
}

// Round 7
// 49.376 us; speedup vs baseline: 1.2494x; 1.1812x over previous
//
#include <hip/hip_runtime.h>
#include <math.h>

#define BATCH 8192
#define DIM 4096

// ---------------------------------------------------------------------------
// Compile-time x-rotation constant tables:
//   X_l(beta) = P0 + sum_mu cos(mu*beta)*A_mu + sin(mu*beta)*B_mu
// Layout (495 floats): l=1 @0 (27), l=2 @27 (125), l=3 @152 (343)
// ---------------------------------------------------------------------------

struct FT { float v[495]; };

constexpr double csqrt(double x) {
  double g = x > 1.0 ? x : 1.0;
  for (int i = 0; i < 50; ++i) g = 0.5 * (g + x / g);
  return g;
}

constexpr void mmc(int n, const double* A, const double* B, double* C) {
  for (int i = 0; i < n; ++i)
    for (int j = 0; j < n; ++j) {
      double s = 0.0;
      for (int k = 0; k < n; ++k) s += A[i * n + k] * B[k * n + j];
      C[i * n + j] = s;
    }
}

constexpr FT compute_ft() {
  FT o{};
  for (int l = 1; l <= 3; ++l) {
    const int n = 2 * l + 1, nn = n * n;
    double JX[49] = {}, UR[49] = {}, UI[49] = {};
    for (int a = 0; a < n - 1; ++a) {
      double m = (double)(a - l);
      double v = 0.5 * csqrt((double)(l * (l + 1)) - m * (m + 1.0));
      JX[(a + 1) * n + a] = v;
      JX[a * n + (a + 1)] = v;
    }
    UR[l * n + l] = 1.0;
    const double s = csqrt(0.5);
    for (int mu = 1; mu <= l; ++mu) {
      double sg = (mu & 1) ? -1.0 : 1.0;
      UR[(l + mu) * n + (l - mu)] = s;
      UR[(l + mu) * n + (l + mu)] = s * sg;
      UI[(l - mu) * n + (l - mu)] = s;
      UI[(l - mu) * n + (l + mu)] = -s * sg;
    }
    double MR[49] = {}, MI[49] = {};
    mmc(n, UR, JX, MR);
    mmc(n, UI, JX, MI);
    double K[49] = {};
    for (int a = 0; a < n; ++a)
      for (int b = 0; b < n; ++b) {
        double acc = 0.0;
        for (int c = 0; c < n; ++c)
          acc += MI[a * n + c] * UR[b * n + c] - MR[a * n + c] * UI[b * n + c];
        K[a * n + b] = acc;
      }
    const double TH = 0.78539816339744830962;
    double S[49] = {}, P[49] = {}, T[49] = {};
    for (int i = 0; i < nn; ++i) S[i] = K[i] * (TH / 16.0);
    for (int i = 0; i < n; ++i) P[i * n + i] = 1.0;
    for (int t = 12; t >= 1; --t) {
      mmc(n, S, P, T);
      double inv = 1.0 / (double)t;
      for (int i = 0; i < nn; ++i) P[i] = T[i] * inv;
      for (int i = 0; i < n; ++i) P[i * n + i] += 1.0;
    }
    for (int q = 0; q < 4; ++q) {
      mmc(n, P, P, T);
      for (int i = 0; i < nn; ++i) P[i] = T[i];
    }
    double acc[7][49] = {};
    double Ek[49] = {}, Et[49] = {};
    for (int i = 0; i < n; ++i) Ek[i * n + i] = 1.0;
    const double r2 = csqrt(0.5);
    const double c8[8] = {1.0, r2, 0.0, -r2, -1.0, -r2, 0.0, r2};
    const double s8[8] = {0.0, r2, 1.0, r2, 0.0, -r2, -1.0, -r2};
    for (int k = 0; k < 8; ++k) {
      for (int i = 0; i < nn; ++i) acc[0][i] += 0.125 * Ek[i];
      for (int mu = 1; mu <= l; ++mu) {
        int a8 = (mu * k) & 7;
        double cc = 0.25 * c8[a8], ss = 0.25 * s8[a8];
        for (int i = 0; i < nn; ++i) {
          acc[2 * mu - 1][i] += cc * Ek[i];
          acc[2 * mu][i] += ss * Ek[i];
        }
      }
      mmc(n, Ek, P, Et);
      for (int i = 0; i < nn; ++i) Ek[i] = Et[i];
    }
    int base = (l == 1) ? 0 : ((l == 2) ? 27 : 152);
    for (int t = 0; t <= 2 * l; ++t)
      for (int i = 0; i < nn; ++i) o.v[base + t * nn + i] = (float)acc[t][i];
  }
  return o;
}

__device__ __constant__ FT c_tb = compute_ft();

typedef float vf4 __attribute__((ext_vector_type(4)));

__device__ __forceinline__ vf4 vfma4(float a, vf4 v, vf4 acc) { return acc + a * v; }

// ---------------------------------------------------------------------------
// Per-lane D-entry e (0..82) for one batch row. All small-array indices are
// compile-time constants (unrolled tt-loop, explicit coef select) -> no
// scratch. Y-rotation angles computed directly via sincosf (no indexed table).
// ---------------------------------------------------------------------------
__device__ __forceinline__ float entry_for(int e, float cb1, float cb2, float cb3,
                                           float sb1, float sb2, float sb3,
                                           float al, float ga) {
  int l, n, basec, i, j;
  if (e < 9)       { l = 1; n = 3; basec = 0;   int r = e;      i = r / 3; j = r - i * 3; }
  else if (e < 34) { l = 2; n = 5; basec = 27;  int r = e - 9;  i = r / 5; j = r - i * 5; }
  else             { l = 3; n = 7; basec = 152; int r = e - 34; i = r / 7; j = r - i * 7; }

  const float* C = c_tb.v + basec;
  const int ip = n - 1 - i, jp = n - 1 - j;
  const int nn = n * n;
  float xij = 0.f, xijp = 0.f, xipj = 0.f, xipjp = 0.f;
  #pragma unroll
  for (int tt = 0; tt < 7; ++tt) {
    if (tt <= 2 * l) {
      float coef;
      if (tt == 0) coef = 1.f;
      else if (tt == 1) coef = cb1;
      else if (tt == 2) coef = sb1;
      else if (tt == 3) coef = cb2;
      else if (tt == 4) coef = sb2;
      else if (tt == 5) coef = cb3;
      else coef = sb3;
      const float* M = C + tt * nn;
      xij   = fmaf(coef, M[i * n + j],   xij);
      xijp  = fmaf(coef, M[i * n + jp],  xijp);
      xipj  = fmaf(coef, M[ip * n + j],  xipj);
      xipjp = fmaf(coef, M[ip * n + jp], xipjp);
    }
  }
  float sa, ca, sg, cg;
  sincosf((float)(i - l) * al, &sa, &ca);
  sincosf((float)(j - l) * ga, &sg, &cg);
  return (ca * xij + sa * xipj) * cg - (ca * xijp + sa * xipjp) * sg;
}

// wave-uniform broadcast of D entry e from the two per-lane regs
__device__ __forceinline__ float dget(float d0, float d1, int e) {
  float s = (e < 64) ? d0 : d1;  // e is compile-time after unroll
  return __builtin_bit_cast(
      float, __builtin_amdgcn_readlane(__builtin_bit_cast(int, s), e & 63));
}

// ---------------------------------------------------------------------------
// Wave-independent streamer: 2048 blocks x 256 threads; each WAVE owns one
// batch row. No LDS, no __syncthreads. 16 x-loads issued first and pinned;
// per-lane D trig overlaps their latency; D consumed via readlane broadcast.
// ---------------------------------------------------------------------------
__global__ __launch_bounds__(256) void rot_wave(
    const float* __restrict__ gamma, const float* __restrict__ beta,
    const float* __restrict__ alpha, const float* __restrict__ x,
    float* __restrict__ out) {
  const int tid = threadIdx.x;
  const int lane = tid & 63;
  const int wv = tid >> 6;
  const size_t b = (size_t)blockIdx.x * 4 + wv;
  const vf4* __restrict__ xin = (const vf4*)x + b * 1024;
  vf4* __restrict__ xo = (vf4*)out + b * 1024;

  // ---- 1. issue ALL 16 x-loads, pin them live ----
  vf4 v0 = xin[lane];
  vf4 v1[3], v2[5], v3[7];
  #pragma unroll
  for (int j = 0; j < 3; ++j) v1[j] = xin[64 + j * 64 + lane];
  #pragma unroll
  for (int j = 0; j < 5; ++j) v2[j] = xin[256 + j * 64 + lane];
  #pragma unroll
  for (int j = 0; j < 7; ++j) v3[j] = xin[576 + j * 64 + lane];
  asm volatile("" ::"v"(v0), "v"(v1[0]), "v"(v1[1]), "v"(v1[2]), "v"(v2[0]),
               "v"(v2[1]), "v"(v2[2]), "v"(v2[3]), "v"(v2[4]), "v"(v3[0]),
               "v"(v3[1]), "v"(v3[2]), "v"(v3[3]), "v"(v3[4]), "v"(v3[5]),
               "v"(v3[6]));

  // ---- 2. per-lane D build (2 entries/lane, overlaps load latency) ----
  const float al = alpha[b], bt = beta[b], ga = gamma[b];
  float cb1, sb1;
  sincosf(bt, &sb1, &cb1);
  const float cb2 = cb1 * cb1 - sb1 * sb1, sb2 = 2.f * sb1 * cb1;
  const float cb3 = cb2 * cb1 - sb2 * sb1, sb3 = sb2 * cb1 + cb2 * sb1;

  const float d0 = entry_for(lane, cb1, cb2, cb3, sb1, sb2, sb3, al, ga);
  int e2 = lane + 64;
  if (e2 > 82) e2 = 82;  // lanes 19..63 compute a dummy (never read)
  const float d1 = entry_for(e2, cb1, cb2, cb3, sb1, sb2, sb3, al, ga);

  // ---- 3. consume: readlane-broadcast D, FMA, nt stores ----
  __builtin_nontemporal_store(v0, &xo[lane]);

  #pragma unroll
  for (int i = 0; i < 3; ++i) {
    vf4 o = (vf4)(0.f);
    #pragma unroll
    for (int j = 0; j < 3; ++j) o = vfma4(dget(d0, d1, i * 3 + j), v1[j], o);
    __builtin_nontemporal_store(o, &xo[64 + i * 64 + lane]);
  }
  #pragma unroll
  for (int i = 0; i < 5; ++i) {
    vf4 o = (vf4)(0.f);
    #pragma unroll
    for (int j = 0; j < 5; ++j) o = vfma4(dget(d0, d1, 9 + i * 5 + j), v2[j], o);
    __builtin_nontemporal_store(o, &xo[256 + i * 64 + lane]);
  }
  #pragma unroll
  for (int i = 0; i < 7; ++i) {
    vf4 o = (vf4)(0.f);
    #pragma unroll
    for (int j = 0; j < 7; ++j) o = vfma4(dget(d0, d1, 34 + i * 7 + j), v3[j], o);
    __builtin_nontemporal_store(o, &xo[576 + i * 64 + lane]);
  }
}

extern "C" void kernel_launch(void* const* d_in, const int* in_sizes, int n_in,
                              void* d_out, int out_size, void* d_ws, size_t ws_size,
                              hipStream_t stream) {
  const float* gamma = (const float*)d_in[0];
  const float* beta  = (const float*)d_in[1];
  const float* alpha = (const float*)d_in[2];
  const float* x     = (const float*)d_in[3];
  float* out = (float*)d_out;

  rot_wave<<<BATCH / 4, 256, 0, stream>>>(gamma, beta, alpha, x, out);
}

// Round 8
// 48.028 us; speedup vs baseline: 1.2845x; 1.0281x over previous
//
#include <hip/hip_runtime.h>
#include <math.h>

#define BATCH 8192
#define DIM 4096

// ---------------------------------------------------------------------------
// Compile-time x-rotation constant tables:
//   X_l(beta) = P0 + sum_mu cos(mu*beta)*A_mu + sin(mu*beta)*B_mu
// Layout (495 floats): l=1 @0 (27), l=2 @27 (125), l=3 @152 (343)
// ---------------------------------------------------------------------------

struct FT { float v[495]; };

constexpr double csqrt(double x) {
  double g = x > 1.0 ? x : 1.0;
  for (int i = 0; i < 50; ++i) g = 0.5 * (g + x / g);
  return g;
}

constexpr void mmc(int n, const double* A, const double* B, double* C) {
  for (int i = 0; i < n; ++i)
    for (int j = 0; j < n; ++j) {
      double s = 0.0;
      for (int k = 0; k < n; ++k) s += A[i * n + k] * B[k * n + j];
      C[i * n + j] = s;
    }
}

constexpr FT compute_ft() {
  FT o{};
  for (int l = 1; l <= 3; ++l) {
    const int n = 2 * l + 1, nn = n * n;
    double JX[49] = {}, UR[49] = {}, UI[49] = {};
    for (int a = 0; a < n - 1; ++a) {
      double m = (double)(a - l);
      double v = 0.5 * csqrt((double)(l * (l + 1)) - m * (m + 1.0));
      JX[(a + 1) * n + a] = v;
      JX[a * n + (a + 1)] = v;
    }
    UR[l * n + l] = 1.0;
    const double s = csqrt(0.5);
    for (int mu = 1; mu <= l; ++mu) {
      double sg = (mu & 1) ? -1.0 : 1.0;
      UR[(l + mu) * n + (l - mu)] = s;
      UR[(l + mu) * n + (l + mu)] = s * sg;
      UI[(l - mu) * n + (l - mu)] = s;
      UI[(l - mu) * n + (l + mu)] = -s * sg;
    }
    double MR[49] = {}, MI[49] = {};
    mmc(n, UR, JX, MR);
    mmc(n, UI, JX, MI);
    double K[49] = {};
    for (int a = 0; a < n; ++a)
      for (int b = 0; b < n; ++b) {
        double acc = 0.0;
        for (int c = 0; c < n; ++c)
          acc += MI[a * n + c] * UR[b * n + c] - MR[a * n + c] * UI[b * n + c];
        K[a * n + b] = acc;
      }
    const double TH = 0.78539816339744830962;
    double S[49] = {}, P[49] = {}, T[49] = {};
    for (int i = 0; i < nn; ++i) S[i] = K[i] * (TH / 16.0);
    for (int i = 0; i < n; ++i) P[i * n + i] = 1.0;
    for (int t = 12; t >= 1; --t) {
      mmc(n, S, P, T);
      double inv = 1.0 / (double)t;
      for (int i = 0; i < nn; ++i) P[i] = T[i] * inv;
      for (int i = 0; i < n; ++i) P[i * n + i] += 1.0;
    }
    for (int q = 0; q < 4; ++q) {
      mmc(n, P, P, T);
      for (int i = 0; i < nn; ++i) P[i] = T[i];
    }
    double acc[7][49] = {};
    double Ek[49] = {}, Et[49] = {};
    for (int i = 0; i < n; ++i) Ek[i * n + i] = 1.0;
    const double r2 = csqrt(0.5);
    const double c8[8] = {1.0, r2, 0.0, -r2, -1.0, -r2, 0.0, r2};
    const double s8[8] = {0.0, r2, 1.0, r2, 0.0, -r2, -1.0, -r2};
    for (int k = 0; k < 8; ++k) {
      for (int i = 0; i < nn; ++i) acc[0][i] += 0.125 * Ek[i];
      for (int mu = 1; mu <= l; ++mu) {
        int a8 = (mu * k) & 7;
        double cc = 0.25 * c8[a8], ss = 0.25 * s8[a8];
        for (int i = 0; i < nn; ++i) {
          acc[2 * mu - 1][i] += cc * Ek[i];
          acc[2 * mu][i] += ss * Ek[i];
        }
      }
      mmc(n, Ek, P, Et);
      for (int i = 0; i < nn; ++i) Ek[i] = Et[i];
    }
    int base = (l == 1) ? 0 : ((l == 2) ? 27 : 152);
    for (int t = 0; t <= 2 * l; ++t)
      for (int i = 0; i < nn; ++i) o.v[base + t * nn + i] = (float)acc[t][i];
  }
  return o;
}

__device__ __constant__ FT c_tb = compute_ft();

typedef float vf4 __attribute__((ext_vector_type(4)));

__device__ __forceinline__ vf4 vfma4(float a, vf4 v, vf4 acc) { return acc + a * v; }

// ---------------------------------------------------------------------------
// Per-lane D-entry e (0..82) for one batch row; all indices compile-time.
// ---------------------------------------------------------------------------
__device__ __forceinline__ float entry_for(int e, float cb1, float cb2, float cb3,
                                           float sb1, float sb2, float sb3,
                                           float al, float ga) {
  int l, n, basec, i, j;
  if (e < 9)       { l = 1; n = 3; basec = 0;   int r = e;      i = r / 3; j = r - i * 3; }
  else if (e < 34) { l = 2; n = 5; basec = 27;  int r = e - 9;  i = r / 5; j = r - i * 5; }
  else             { l = 3; n = 7; basec = 152; int r = e - 34; i = r / 7; j = r - i * 7; }

  const float* C = c_tb.v + basec;
  const int ip = n - 1 - i, jp = n - 1 - j;
  const int nn = n * n;
  float xij = 0.f, xijp = 0.f, xipj = 0.f, xipjp = 0.f;
  #pragma unroll
  for (int tt = 0; tt < 7; ++tt) {
    if (tt <= 2 * l) {
      float coef;
      if (tt == 0) coef = 1.f;
      else if (tt == 1) coef = cb1;
      else if (tt == 2) coef = sb1;
      else if (tt == 3) coef = cb2;
      else if (tt == 4) coef = sb2;
      else if (tt == 5) coef = cb3;
      else coef = sb3;
      const float* M = C + tt * nn;
      xij   = fmaf(coef, M[i * n + j],   xij);
      xijp  = fmaf(coef, M[i * n + jp],  xijp);
      xipj  = fmaf(coef, M[ip * n + j],  xipj);
      xipjp = fmaf(coef, M[ip * n + jp], xipjp);
    }
  }
  float sa, ca, sg, cg;
  sincosf((float)(i - l) * al, &sa, &ca);
  sincosf((float)(j - l) * ga, &sg, &cg);
  return (ca * xij + sa * xipj) * cg - (ca * xijp + sa * xipjp) * sg;
}

__device__ __forceinline__ float dget(float d0, float d1, int e) {
  float s = (e < 64) ? d0 : d1;  // e is compile-time after unroll
  return __builtin_bit_cast(
      float, __builtin_amdgcn_readlane(__builtin_bit_cast(int, s), e & 63));
}

#define PIN16(v0, v1, v2, v3)                                                  \
  asm volatile("" ::"v"(v0), "v"(v1[0]), "v"(v1[1]), "v"(v1[2]), "v"(v2[0]),   \
               "v"(v2[1]), "v"(v2[2]), "v"(v2[3]), "v"(v2[4]), "v"(v3[0]),     \
               "v"(v3[1]), "v"(v3[2]), "v"(v3[3]), "v"(v3[4]), "v"(v3[5]),     \
               "v"(v3[6]))

// ---------------------------------------------------------------------------
// 2-row software-pipelined wave streamer. 1024 blocks x 256 threads; each
// wave handles rows bA and bA+4096. Angle loads issue FIRST (so the trig's
// vmcnt wait does not drain the x-loads); loads B issue before store A.
// ---------------------------------------------------------------------------
__global__ __launch_bounds__(256) void rot_pipe(
    const float* __restrict__ gamma, const float* __restrict__ beta,
    const float* __restrict__ alpha, const float* __restrict__ x,
    float* __restrict__ out) {
  const int tid = threadIdx.x;
  const int lane = tid & 63;
  const int wv = tid >> 6;
  const size_t bA = (size_t)blockIdx.x * 4 + wv;
  const size_t bB = bA + BATCH / 2;

  // ---- 0. angle loads FIRST (6 loads; trig waits only on these) ----
  const float alA = alpha[bA], btA = beta[bA], gaA = gamma[bA];
  const float alB = alpha[bB], btB = beta[bB], gaB = gamma[bB];

  const vf4* __restrict__ xinA = (const vf4*)x + bA * 1024;
  const vf4* __restrict__ xinB = (const vf4*)x + bB * 1024;
  vf4* __restrict__ xoA = (vf4*)out + bA * 1024;
  vf4* __restrict__ xoB = (vf4*)out + bB * 1024;

  // ---- 1. issue 16 x-loads for row A, pin ----
  vf4 a0 = xinA[lane];
  vf4 a1[3], a2[5], a3[7];
  #pragma unroll
  for (int j = 0; j < 3; ++j) a1[j] = xinA[64 + j * 64 + lane];
  #pragma unroll
  for (int j = 0; j < 5; ++j) a2[j] = xinA[256 + j * 64 + lane];
  #pragma unroll
  for (int j = 0; j < 7; ++j) a3[j] = xinA[576 + j * 64 + lane];
  PIN16(a0, a1, a2, a3);

  // ---- 2. D-build A (overlaps A's load latency) ----
  float cb1, sb1;
  sincosf(btA, &sb1, &cb1);
  float cb2 = cb1 * cb1 - sb1 * sb1, sb2 = 2.f * sb1 * cb1;
  float cb3 = cb2 * cb1 - sb2 * sb1, sb3 = sb2 * cb1 + cb2 * sb1;
  const float d0A = entry_for(lane, cb1, cb2, cb3, sb1, sb2, sb3, alA, gaA);
  int e2 = lane + 64;
  if (e2 > 82) e2 = 82;
  const float d1A = entry_for(e2, cb1, cb2, cb3, sb1, sb2, sb3, alA, gaA);

  // ---- 3. issue 16 x-loads for row B, pin (32 loads in flight) ----
  vf4 q0 = xinB[lane];
  vf4 q1[3], q2[5], q3[7];
  #pragma unroll
  for (int j = 0; j < 3; ++j) q1[j] = xinB[64 + j * 64 + lane];
  #pragma unroll
  for (int j = 0; j < 5; ++j) q2[j] = xinB[256 + j * 64 + lane];
  #pragma unroll
  for (int j = 0; j < 7; ++j) q3[j] = xinB[576 + j * 64 + lane];
  PIN16(q0, q1, q2, q3);

  // ---- 4. consume A (vmcnt waits on A only; B stays in flight) ----
  __builtin_nontemporal_store(a0, &xoA[lane]);
  #pragma unroll
  for (int i = 0; i < 3; ++i) {
    vf4 o = (vf4)(0.f);
    #pragma unroll
    for (int j = 0; j < 3; ++j) o = vfma4(dget(d0A, d1A, i * 3 + j), a1[j], o);
    __builtin_nontemporal_store(o, &xoA[64 + i * 64 + lane]);
  }
  #pragma unroll
  for (int i = 0; i < 5; ++i) {
    vf4 o = (vf4)(0.f);
    #pragma unroll
    for (int j = 0; j < 5; ++j) o = vfma4(dget(d0A, d1A, 9 + i * 5 + j), a2[j], o);
    __builtin_nontemporal_store(o, &xoA[256 + i * 64 + lane]);
  }
  #pragma unroll
  for (int i = 0; i < 7; ++i) {
    vf4 o = (vf4)(0.f);
    #pragma unroll
    for (int j = 0; j < 7; ++j) o = vfma4(dget(d0A, d1A, 34 + i * 7 + j), a3[j], o);
    __builtin_nontemporal_store(o, &xoA[576 + i * 64 + lane]);
  }

  // ---- 5. D-build B (overlaps B's load latency + A's store drain) ----
  sincosf(btB, &sb1, &cb1);
  cb2 = cb1 * cb1 - sb1 * sb1; sb2 = 2.f * sb1 * cb1;
  cb3 = cb2 * cb1 - sb2 * sb1; sb3 = sb2 * cb1 + cb2 * sb1;
  const float d0B = entry_for(lane, cb1, cb2, cb3, sb1, sb2, sb3, alB, gaB);
  const float d1B = entry_for(e2, cb1, cb2, cb3, sb1, sb2, sb3, alB, gaB);

  // ---- 6. consume B ----
  __builtin_nontemporal_store(q0, &xoB[lane]);
  #pragma unroll
  for (int i = 0; i < 3; ++i) {
    vf4 o = (vf4)(0.f);
    #pragma unroll
    for (int j = 0; j < 3; ++j) o = vfma4(dget(d0B, d1B, i * 3 + j), q1[j], o);
    __builtin_nontemporal_store(o, &xoB[64 + i * 64 + lane]);
  }
  #pragma unroll
  for (int i = 0; i < 5; ++i) {
    vf4 o = (vf4)(0.f);
    #pragma unroll
    for (int j = 0; j < 5; ++j) o = vfma4(dget(d0B, d1B, 9 + i * 5 + j), q2[j], o);
    __builtin_nontemporal_store(o, &xoB[256 + i * 64 + lane]);
  }
  #pragma unroll
  for (int i = 0; i < 7; ++i) {
    vf4 o = (vf4)(0.f);
    #pragma unroll
    for (int j = 0; j < 7; ++j) o = vfma4(dget(d0B, d1B, 34 + i * 7 + j), q3[j], o);
    __builtin_nontemporal_store(o, &xoB[576 + i * 64 + lane]);
  }
}

extern "C" void kernel_launch(void* const* d_in, const int* in_sizes, int n_in,
                              void* d_out, int out_size, void* d_ws, size_t ws_size,
                              hipStream_t stream) {
  const float* gamma = (const float*)d_in[0];
  const float* beta  = (const float*)d_in[1];
  const float* alpha = (const float*)d_in[2];
  const float* x     = (const float*)d_in[3];
  float* out = (float*)d_out;

  rot_pipe<<<BATCH / 8, 256, 0, stream>>>(gamma, beta, alpha, x, out);
}

// Round 9
// 43.985 us; speedup vs baseline: 1.4026x; 1.0919x over previous
//
#include <hip/hip_runtime.h>
#include <math.h>

#define BATCH 8192
#define DIM 4096

// ---------------------------------------------------------------------------
// Compile-time x-rotation constant tables:
//   X_l(beta) = P0 + sum_mu cos(mu*beta)*A_mu + sin(mu*beta)*B_mu
// Layout (495 floats): l=1 @0 (27), l=2 @27 (125), l=3 @152 (343)
// ---------------------------------------------------------------------------

struct FT { float v[495]; };

constexpr double csqrt(double x) {
  double g = x > 1.0 ? x : 1.0;
  for (int i = 0; i < 50; ++i) g = 0.5 * (g + x / g);
  return g;
}

constexpr void mmc(int n, const double* A, const double* B, double* C) {
  for (int i = 0; i < n; ++i)
    for (int j = 0; j < n; ++j) {
      double s = 0.0;
      for (int k = 0; k < n; ++k) s += A[i * n + k] * B[k * n + j];
      C[i * n + j] = s;
    }
}

constexpr FT compute_ft() {
  FT o{};
  for (int l = 1; l <= 3; ++l) {
    const int n = 2 * l + 1, nn = n * n;
    double JX[49] = {}, UR[49] = {}, UI[49] = {};
    for (int a = 0; a < n - 1; ++a) {
      double m = (double)(a - l);
      double v = 0.5 * csqrt((double)(l * (l + 1)) - m * (m + 1.0));
      JX[(a + 1) * n + a] = v;
      JX[a * n + (a + 1)] = v;
    }
    UR[l * n + l] = 1.0;
    const double s = csqrt(0.5);
    for (int mu = 1; mu <= l; ++mu) {
      double sg = (mu & 1) ? -1.0 : 1.0;
      UR[(l + mu) * n + (l - mu)] = s;
      UR[(l + mu) * n + (l + mu)] = s * sg;
      UI[(l - mu) * n + (l - mu)] = s;
      UI[(l - mu) * n + (l + mu)] = -s * sg;
    }
    double MR[49] = {}, MI[49] = {};
    mmc(n, UR, JX, MR);
    mmc(n, UI, JX, MI);
    double K[49] = {};
    for (int a = 0; a < n; ++a)
      for (int b = 0; b < n; ++b) {
        double acc = 0.0;
        for (int c = 0; c < n; ++c)
          acc += MI[a * n + c] * UR[b * n + c] - MR[a * n + c] * UI[b * n + c];
        K[a * n + b] = acc;
      }
    const double TH = 0.78539816339744830962;
    double S[49] = {}, P[49] = {}, T[49] = {};
    for (int i = 0; i < nn; ++i) S[i] = K[i] * (TH / 16.0);
    for (int i = 0; i < n; ++i) P[i * n + i] = 1.0;
    for (int t = 12; t >= 1; --t) {
      mmc(n, S, P, T);
      double inv = 1.0 / (double)t;
      for (int i = 0; i < nn; ++i) P[i] = T[i] * inv;
      for (int i = 0; i < n; ++i) P[i * n + i] += 1.0;
    }
    for (int q = 0; q < 4; ++q) {
      mmc(n, P, P, T);
      for (int i = 0; i < nn; ++i) P[i] = T[i];
    }
    double acc[7][49] = {};
    double Ek[49] = {}, Et[49] = {};
    for (int i = 0; i < n; ++i) Ek[i * n + i] = 1.0;
    const double r2 = csqrt(0.5);
    const double c8[8] = {1.0, r2, 0.0, -r2, -1.0, -r2, 0.0, r2};
    const double s8[8] = {0.0, r2, 1.0, r2, 0.0, -r2, -1.0, -r2};
    for (int k = 0; k < 8; ++k) {
      for (int i = 0; i < nn; ++i) acc[0][i] += 0.125 * Ek[i];
      for (int mu = 1; mu <= l; ++mu) {
        int a8 = (mu * k) & 7;
        double cc = 0.25 * c8[a8], ss = 0.25 * s8[a8];
        for (int i = 0; i < nn; ++i) {
          acc[2 * mu - 1][i] += cc * Ek[i];
          acc[2 * mu][i] += ss * Ek[i];
        }
      }
      mmc(n, Ek, P, Et);
      for (int i = 0; i < nn; ++i) Ek[i] = Et[i];
    }
    int base = (l == 1) ? 0 : ((l == 2) ? 27 : 152);
    for (int t = 0; t <= 2 * l; ++t)
      for (int i = 0; i < nn; ++i) o.v[base + t * nn + i] = (float)acc[t][i];
  }
  return o;
}

__device__ __constant__ FT c_tb = compute_ft();

typedef float vf4 __attribute__((ext_vector_type(4)));

__device__ __forceinline__ vf4 vfma4(float a, vf4 v, vf4 acc) { return acc + a * v; }

// ---------------------------------------------------------------------------
// Per-lane D-entry e (0..82); all hot indices resolve at compile time after
// unrolling. e is wave-uniform in its l-class here (one class per wave).
// ---------------------------------------------------------------------------
__device__ __forceinline__ float entry_for(int e, float cb1, float cb2, float cb3,
                                           float sb1, float sb2, float sb3,
                                           float al, float ga) {
  int l, n, basec, i, j;
  if (e < 9)       { l = 1; n = 3; basec = 0;   int r = e;      i = r / 3; j = r - i * 3; }
  else if (e < 34) { l = 2; n = 5; basec = 27;  int r = e - 9;  i = r / 5; j = r - i * 5; }
  else             { l = 3; n = 7; basec = 152; int r = e - 34; i = r / 7; j = r - i * 7; }

  const float* C = c_tb.v + basec;
  const int ip = n - 1 - i, jp = n - 1 - j;
  const int nn = n * n;
  float xij = 0.f, xijp = 0.f, xipj = 0.f, xipjp = 0.f;
  #pragma unroll
  for (int tt = 0; tt < 7; ++tt) {
    if (tt <= 2 * l) {
      float coef;
      if (tt == 0) coef = 1.f;
      else if (tt == 1) coef = cb1;
      else if (tt == 2) coef = sb1;
      else if (tt == 3) coef = cb2;
      else if (tt == 4) coef = sb2;
      else if (tt == 5) coef = cb3;
      else coef = sb3;
      const float* M = C + tt * nn;
      xij   = fmaf(coef, M[i * n + j],   xij);
      xijp  = fmaf(coef, M[i * n + jp],  xijp);
      xipj  = fmaf(coef, M[ip * n + j],  xipj);
      xipjp = fmaf(coef, M[ip * n + jp], xipjp);
    }
  }
  float sa, ca, sg, cg;
  sincosf((float)(i - l) * al, &sa, &ca);
  sincosf((float)(j - l) * ga, &sg, &cg);
  return (ca * xij + sa * xipj) * cg - (ca * xijp + sa * xipjp) * sg;
}

// broadcast D entry k (0..63) held in lane k's register d
__device__ __forceinline__ float dget1(float d, int k) {
  return __builtin_bit_cast(
      float, __builtin_amdgcn_readlane(__builtin_bit_cast(int, d), k));
}

// ---------------------------------------------------------------------------
// Segment-split streamer: 1 block = 192 threads = 3 independent waves, one
// batch row per block. wave0: l=0 copy + l=1 (4 vf4/lane); wave1: l=2 (5);
// wave2: l=3 (7). Low VGPR -> 8 waves/SIMD; ~2x resident rows vs r8.
// No LDS, no barriers. Loads issue first; per-lane D trig overlaps latency.
// ---------------------------------------------------------------------------
__global__ __launch_bounds__(192) void rot_seg(
    const float* __restrict__ gamma, const float* __restrict__ beta,
    const float* __restrict__ alpha, const float* __restrict__ x,
    float* __restrict__ out) {
  const int tid = threadIdx.x;
  const int lane = tid & 63;
  const int wv = tid >> 6;  // 0,1,2
  const size_t b = (size_t)blockIdx.x;
  const vf4* __restrict__ xin = (const vf4*)x + b * 1024;
  vf4* __restrict__ xo = (vf4*)out + b * 1024;

  // angle scalar loads (SGPR, uniform)
  const float al = alpha[b], bt = beta[b], ga = gamma[b];

  if (wv == 0) {
    // ---- loads first: l0 (1) + l1 (3) ----
    vf4 v0 = xin[lane];
    vf4 v1[3];
    #pragma unroll
    for (int j = 0; j < 3; ++j) v1[j] = xin[64 + j * 64 + lane];
    asm volatile("" ::"v"(v0), "v"(v1[0]), "v"(v1[1]), "v"(v1[2]));

    // ---- D build (l=1: 9 entries, lanes 0..8), overlaps load latency ----
    float cb1, sb1;
    sincosf(bt, &sb1, &cb1);
    int e = lane < 9 ? lane : 8;
    const float d = entry_for(e, cb1, 0.f, 0.f, sb1, 0.f, 0.f, al, ga);

    __builtin_nontemporal_store(v0, &xo[lane]);
    #pragma unroll
    for (int i = 0; i < 3; ++i) {
      vf4 o = (vf4)(0.f);
      #pragma unroll
      for (int j = 0; j < 3; ++j) o = vfma4(dget1(d, i * 3 + j), v1[j], o);
      __builtin_nontemporal_store(o, &xo[64 + i * 64 + lane]);
    }
  } else if (wv == 1) {
    // ---- loads first: l2 (5) ----
    vf4 v2[5];
    #pragma unroll
    for (int j = 0; j < 5; ++j) v2[j] = xin[256 + j * 64 + lane];
    asm volatile("" ::"v"(v2[0]), "v"(v2[1]), "v"(v2[2]), "v"(v2[3]),
                 "v"(v2[4]));

    // ---- D build (l=2: 25 entries, lanes 0..24) ----
    float cb1, sb1;
    sincosf(bt, &sb1, &cb1);
    const float cb2 = cb1 * cb1 - sb1 * sb1, sb2 = 2.f * sb1 * cb1;
    int e = 9 + (lane < 25 ? lane : 24);
    const float d = entry_for(e, cb1, cb2, 0.f, sb1, sb2, 0.f, al, ga);

    #pragma unroll
    for (int i = 0; i < 5; ++i) {
      vf4 o = (vf4)(0.f);
      #pragma unroll
      for (int j = 0; j < 5; ++j) o = vfma4(dget1(d, i * 5 + j), v2[j], o);
      __builtin_nontemporal_store(o, &xo[256 + i * 64 + lane]);
    }
  } else {
    // ---- loads first: l3 (7) ----
    vf4 v3[7];
    #pragma unroll
    for (int j = 0; j < 7; ++j) v3[j] = xin[576 + j * 64 + lane];
    asm volatile("" ::"v"(v3[0]), "v"(v3[1]), "v"(v3[2]), "v"(v3[3]),
                 "v"(v3[4]), "v"(v3[5]), "v"(v3[6]));

    // ---- D build (l=3: 49 entries, lanes 0..48) ----
    float cb1, sb1;
    sincosf(bt, &sb1, &cb1);
    const float cb2 = cb1 * cb1 - sb1 * sb1, sb2 = 2.f * sb1 * cb1;
    const float cb3 = cb2 * cb1 - sb2 * sb1, sb3 = sb2 * cb1 + cb2 * sb1;
    int e = 34 + (lane < 49 ? lane : 48);
    const float d = entry_for(e, cb1, cb2, cb3, sb1, sb2, sb3, al, ga);

    #pragma unroll
    for (int i = 0; i < 7; ++i) {
      vf4 o = (vf4)(0.f);
      #pragma unroll
      for (int j = 0; j < 7; ++j) o = vfma4(dget1(d, i * 7 + j), v3[j], o);
      __builtin_nontemporal_store(o, &xo[576 + i * 64 + lane]);
    }
  }
}

extern "C" void kernel_launch(void* const* d_in, const int* in_sizes, int n_in,
                              void* d_out, int out_size, void* d_ws, size_t ws_size,
                              hipStream_t stream) {
  const float* gamma = (const float*)d_in[0];
  const float* beta  = (const float*)d_in[1];
  const float* alpha = (const float*)d_in[2];
  const float* x     = (const float*)d_in[3];
  float* out = (float*)d_out;

  rot_seg<<<BATCH, 192, 0, stream>>>(gamma, beta, alpha, x, out);
}